// Round 2
// baseline (313.982 us; speedup 1.0000x reference)
//
#include <hip/hip_runtime.h>
#include <hip/hip_bf16.h>
#include <stdint.h>
#include <stddef.h>

// HoloLinear: out[b,s,o] = sum_h (sum_i x[b,s,i]*basis[h,i]) * (amp[o,h]*cos(phase[o,h]))
// Factored two-stage bf16 MFMA pipeline:
//   resonance[16384,256] = x_f32[16384,2048] @ basis_bf16[256,2048]^T   (A read fp32, cvt in-reg)
//   out[16384,8192]      = resonance_bf16 @ wreal_bf16[8192,256]^T
//
// gemm1: 32x256 tile, A-fragments loaded direct from global (fp32, no LDS for A),
//        B staged via global_load_lds width-16. Grid 512 -> 2 blocks/CU.
// gemm2: m97-style 128x128 tile, BK=32, 4 waves, + bijective XCD swizzle (T1).

typedef __bf16 bf16x8 __attribute__((ext_vector_type(8)));
typedef float  f32x4  __attribute__((ext_vector_type(4)));
typedef unsigned short u16x8 __attribute__((ext_vector_type(8)));

#define M_ROWS 16384
#define K_IN   2048
#define N_OUT  8192
#define N_HARM 256

__device__ inline unsigned short f2bf(float f) {
    union { float f; uint32_t u; } c; c.f = f;
    uint32_t u = c.u;
    uint32_t r = (u + 0x7fffu + ((u >> 16) & 1u)) >> 16;  // RNE
    return (unsigned short)r;
}

__device__ inline bf16x8 cvt8(float4 a, float4 b) {
    bf16x8 r;
    r[0] = (__bf16)a.x; r[1] = (__bf16)a.y; r[2] = (__bf16)a.z; r[3] = (__bf16)a.w;
    r[4] = (__bf16)b.x; r[5] = (__bf16)b.y; r[6] = (__bf16)b.z; r[7] = (__bf16)b.w;
    return r;
}

// ---- fp32 -> bf16 conversion, 8 elements/thread (basis only) ----
__global__ __launch_bounds__(256) void cvt_bf16(const float* __restrict__ in,
                                                unsigned short* __restrict__ out) {
    size_t i = ((size_t)blockIdx.x * 256 + threadIdx.x) * 8;
    float4 v0 = *(const float4*)(in + i);
    float4 v1 = *(const float4*)(in + i + 4);
    u16x8 o;
    o[0] = f2bf(v0.x); o[1] = f2bf(v0.y); o[2] = f2bf(v0.z); o[3] = f2bf(v0.w);
    o[4] = f2bf(v1.x); o[5] = f2bf(v1.y); o[6] = f2bf(v1.z); o[7] = f2bf(v1.w);
    *(u16x8*)(out + i) = o;
}

// ---- w_real = amp * cos(phase) -> bf16, 8 elements/thread ----
__global__ __launch_bounds__(256) void wreal_bf16(const float* __restrict__ phase,
                                                  const float* __restrict__ amp,
                                                  unsigned short* __restrict__ out) {
    size_t i = ((size_t)blockIdx.x * 256 + threadIdx.x) * 8;
    float4 p0 = *(const float4*)(phase + i);
    float4 p1 = *(const float4*)(phase + i + 4);
    float4 a0 = *(const float4*)(amp + i);
    float4 a1 = *(const float4*)(amp + i + 4);
    u16x8 o;
    o[0] = f2bf(a0.x * cosf(p0.x)); o[1] = f2bf(a0.y * cosf(p0.y));
    o[2] = f2bf(a0.z * cosf(p0.z)); o[3] = f2bf(a0.w * cosf(p0.w));
    o[4] = f2bf(a1.x * cosf(p1.x)); o[5] = f2bf(a1.y * cosf(p1.y));
    o[6] = f2bf(a1.z * cosf(p1.z)); o[7] = f2bf(a1.w * cosf(p1.w));
    *(u16x8*)(out + i) = o;
}

// ---- gemm1: resonance[M,256] = x_f32[M,2048] @ basis_bf16[256,2048]^T ----
// 32x256 tile, grid(M/32)=512, 4 waves (wave wc covers cols wc*64..+63, all 32 rows).
// A fragments: direct global fp32 loads (16B/lane; 4 lanes of a 16-group cover one
// contiguous 128B row segment -> coalesced; shared across waves via L1/L2).
__global__ __launch_bounds__(256) void gemm1_fused(const float* __restrict__ A,
                                                   const unsigned short* __restrict__ B,
                                                   unsigned short* __restrict__ C) {
    __shared__ unsigned short Bs[256 * 32];

    const int tid  = threadIdx.x;
    const int lane = tid & 63;
    const int wv   = tid >> 6;
    const int wc   = wv;               // wave col 0..3
    const int bm0  = blockIdx.x * 32;

    const int frow = lane & 15;        // fragment row (A) / col (B)
    const int kgrp = (lane >> 4) * 8;  // contiguous 8-k segment per 16-lane group

    // B staging: 4 issues x (256 thr x 16B) cover 256 rows x 32 cols bf16
    const int srow = tid >> 2;         // 0..63 within issue
    const int scol = (tid & 3) * 8;
    const unsigned short* gB[4];
#pragma unroll
    for (int i = 0; i < 4; ++i)
        gB[i] = B + (size_t)(i * 64 + srow) * K_IN + scol;
    unsigned short* lB[4];
#pragma unroll
    for (int i = 0; i < 4; ++i)
        lB[i] = Bs + i * 2048 + wv * 512;

    // A fragment global pointers: row = i*16 + frow, k-base = kgrp
    const float* gA[2];
#pragma unroll
    for (int i = 0; i < 2; ++i)
        gA[i] = A + (size_t)(bm0 + i * 16 + frow) * K_IN + kgrp;

    f32x4 acc[2][4];
#pragma unroll
    for (int i = 0; i < 2; ++i)
#pragma unroll
        for (int j = 0; j < 4; ++j) acc[i][j] = (f32x4){0.f, 0.f, 0.f, 0.f};

    for (int k0 = 0; k0 < K_IN; k0 += 32) {
        // issue A-frag loads first (independent of LDS) so latency hides under staging
        float4 fa0[2], fa1[2];
#pragma unroll
        for (int i = 0; i < 2; ++i) {
            fa0[i] = *(const float4*)(gA[i] + k0);
            fa1[i] = *(const float4*)(gA[i] + k0 + 4);
        }
        __syncthreads();
#pragma unroll
        for (int i = 0; i < 4; ++i)
            __builtin_amdgcn_global_load_lds((const __attribute__((address_space(1))) void*)(gB[i] + k0),
                                             (__attribute__((address_space(3))) void*)lB[i], 16, 0, 0);
        __syncthreads();

        bf16x8 bfr[4];
#pragma unroll
        for (int j = 0; j < 4; ++j)
            bfr[j] = *(const bf16x8*)(&Bs[(wc * 64 + j * 16 + frow) * 32 + kgrp]);

        bf16x8 af[2];
#pragma unroll
        for (int i = 0; i < 2; ++i) af[i] = cvt8(fa0[i], fa1[i]);

#pragma unroll
        for (int i = 0; i < 2; ++i)
#pragma unroll
            for (int j = 0; j < 4; ++j)
                acc[i][j] = __builtin_amdgcn_mfma_f32_16x16x32_bf16(af[i], bfr[j], acc[i][j], 0, 0, 0);
    }

    // C/D layout: col = lane&15, row = (lane>>4)*4 + r
#pragma unroll
    for (int i = 0; i < 2; ++i)
#pragma unroll
        for (int j = 0; j < 4; ++j)
#pragma unroll
            for (int r = 0; r < 4; ++r) {
                int row = bm0 + i * 16 + (lane >> 4) * 4 + r;
                int col = wc * 64 + j * 16 + (lane & 15);
                C[(size_t)row * N_HARM + col] = f2bf(acc[i][j][r]);
            }
}

// ---- gemm2: C[M][NCOLS] = A[M][K] @ B[NCOLS][K]^T  (bf16 in, fp32 out) ----
// 128x128 tile, BK=32, 256 threads = 4 waves (2x2 of 64x64), 16x16x32 MFMA.
// Bijective XCD swizzle on flat block id (nwg % 8 == 0).
template<int K, int NCOLS>
__global__ __launch_bounds__(256) void gemm_bt(const unsigned short* __restrict__ A,
                                               const unsigned short* __restrict__ B,
                                               float* __restrict__ Cv) {
    __shared__ unsigned short As[128 * 32];
    __shared__ unsigned short Bs[128 * 32];

    const int tid  = threadIdx.x;
    const int lane = tid & 63;
    const int wv   = tid >> 6;
    const int wr   = wv >> 1;
    const int wc   = wv & 1;

    // XCD swizzle: flat -> contiguous chunk per XCD
    const int nwgx = gridDim.x;
    const int flat = blockIdx.y * nwgx + blockIdx.x;
    const int cpx  = (nwgx * gridDim.y) >> 3;
    const int swz  = (flat & 7) * cpx + (flat >> 3);
    const int bm0  = (swz / nwgx) * 128;
    const int bn0  = (swz % nwgx) * 128;

    const int srow = tid >> 2;
    const int scol = (tid & 3) * 8;
    const unsigned short* gA0 = A + (size_t)(bm0 + srow) * K + scol;
    const unsigned short* gA1 = gA0 + (size_t)64 * K;
    const unsigned short* gB0 = B + (size_t)(bn0 + srow) * K + scol;
    const unsigned short* gB1 = gB0 + (size_t)64 * K;
    unsigned short* lA0 = As + wv * 512;
    unsigned short* lA1 = As + 2048 + wv * 512;
    unsigned short* lB0 = Bs + wv * 512;
    unsigned short* lB1 = Bs + 2048 + wv * 512;

    f32x4 acc[4][4];
#pragma unroll
    for (int i = 0; i < 4; ++i)
#pragma unroll
        for (int j = 0; j < 4; ++j) acc[i][j] = (f32x4){0.f, 0.f, 0.f, 0.f};

    const int frow = lane & 15;
    const int kseg = (lane >> 4) * 8;

    for (int k0 = 0; k0 < K; k0 += 32) {
        __syncthreads();
        __builtin_amdgcn_global_load_lds((const __attribute__((address_space(1))) void*)(gA0 + k0),
                                         (__attribute__((address_space(3))) void*)lA0, 16, 0, 0);
        __builtin_amdgcn_global_load_lds((const __attribute__((address_space(1))) void*)(gA1 + k0),
                                         (__attribute__((address_space(3))) void*)lA1, 16, 0, 0);
        __builtin_amdgcn_global_load_lds((const __attribute__((address_space(1))) void*)(gB0 + k0),
                                         (__attribute__((address_space(3))) void*)lB0, 16, 0, 0);
        __builtin_amdgcn_global_load_lds((const __attribute__((address_space(1))) void*)(gB1 + k0),
                                         (__attribute__((address_space(3))) void*)lB1, 16, 0, 0);
        __syncthreads();

        bf16x8 af[4], bfr[4];
#pragma unroll
        for (int i = 0; i < 4; ++i) {
            af[i]  = *(const bf16x8*)(&As[(wr * 64 + i * 16 + frow) * 32 + kseg]);
            bfr[i] = *(const bf16x8*)(&Bs[(wc * 64 + i * 16 + frow) * 32 + kseg]);
        }
#pragma unroll
        for (int i = 0; i < 4; ++i)
#pragma unroll
            for (int j = 0; j < 4; ++j)
                acc[i][j] = __builtin_amdgcn_mfma_f32_16x16x32_bf16(af[i], bfr[j], acc[i][j], 0, 0, 0);
    }

#pragma unroll
    for (int i = 0; i < 4; ++i)
#pragma unroll
        for (int j = 0; j < 4; ++j)
#pragma unroll
            for (int r = 0; r < 4; ++r) {
                int row = bm0 + wr * 64 + i * 16 + (lane >> 4) * 4 + r;
                int col = bn0 + wc * 64 + j * 16 + (lane & 15);
                Cv[(size_t)row * NCOLS + col] = acc[i][j][r];
            }
}

extern "C" void kernel_launch(void* const* d_in, const int* in_sizes, int n_in,
                              void* d_out, int out_size, void* d_ws, size_t ws_size,
                              hipStream_t stream) {
    const float* x     = (const float*)d_in[0];   // [4,4096,2048]
    const float* basis = (const float*)d_in[1];   // [256,2048]
    const float* phase = (const float*)d_in[2];   // [8192,256]
    const float* amp   = (const float*)d_in[3];   // [8192,256]
    float* out = (float*)d_out;                   // [4,4096,8192] fp32

    char* ws = (char*)d_ws;
    unsigned short* bb  = (unsigned short*)(ws);             // basis bf16: 1048576 B
    unsigned short* wrb = (unsigned short*)(ws + 1048576);   // wreal bf16: 4194304 B
    unsigned short* rb  = (unsigned short*)(ws + 5242880);   // resonance:  8388608 B

    // basis: 256*2048 = 524288 elems -> 256 blocks
    cvt_bf16<<<dim3(256), dim3(256), 0, stream>>>(basis, bb);
    // wreal: 8192*256 = 2097152 elems -> 1024 blocks
    wreal_bf16<<<dim3(1024), dim3(256), 0, stream>>>(phase, amp, wrb);

    // resonance[16384,256] = x @ bb^T  (A fp32 direct), 32-row tiles -> 512 blocks
    gemm1_fused<<<dim3(M_ROWS / 32), dim3(256), 0, stream>>>(x, bb, rb);
    // out[16384,8192] = rb @ wrb^T     (K=256, N=8192)
    gemm_bt<256, 8192><<<dim3(N_OUT / 128, M_ROWS / 128), dim3(256), 0, stream>>>(rb, wrb, out);
}

// Round 3
// 207.308 us; speedup vs baseline: 1.5146x; 1.5146x over previous
//
#include <hip/hip_runtime.h>
#include <hip/hip_bf16.h>
#include <stdint.h>
#include <stddef.h>

// HoloLinear factored bf16 MFMA pipeline:
//   resonance[16384,256] = x_f32[16384,2048] @ basis_bf16[256,2048]^T
//   out[16384,8192]      = resonance_bf16 @ wreal_bf16[8192,256]^T
//
// gemm1: fused fp32->bf16: x staged fp32 via global_load_lds (pre-swizzled
//        source, linear LDS dest; XOR-swizzled reads), 32x256 tile, BK=64,
//        32x32x16 MFMA, 2-phase double-buffered prefetch. Grid 512.
// gemm2: round-1-verified 128x128 / BK=32 structure + 2-phase dbuf prefetch.

typedef __bf16 bf16x8 __attribute__((ext_vector_type(8)));
typedef float  f32x4  __attribute__((ext_vector_type(4)));
typedef float  f32x16 __attribute__((ext_vector_type(16)));
typedef unsigned short u16x8 __attribute__((ext_vector_type(8)));

#define M_ROWS 16384
#define K_IN   2048
#define N_OUT  8192
#define N_HARM 256

__device__ inline unsigned short f2bf(float f) {
    union { float f; uint32_t u; } c; c.f = f;
    uint32_t u = c.u;
    uint32_t r = (u + 0x7fffu + ((u >> 16) & 1u)) >> 16;  // RNE
    return (unsigned short)r;
}

__device__ inline bf16x8 cvt8(f32x4 a, f32x4 b) {
    bf16x8 r;
    r[0] = (__bf16)a[0]; r[1] = (__bf16)a[1]; r[2] = (__bf16)a[2]; r[3] = (__bf16)a[3];
    r[4] = (__bf16)b[0]; r[5] = (__bf16)b[1]; r[6] = (__bf16)b[2]; r[7] = (__bf16)b[3];
    return r;
}

#define GLDS(src, dst) \
    __builtin_amdgcn_global_load_lds((const __attribute__((address_space(1))) void*)(src), \
                                     (__attribute__((address_space(3))) void*)(dst), 16, 0, 0)

// ---- fp32 -> bf16 conversion (basis) ----
__global__ __launch_bounds__(256) void cvt_bf16(const float* __restrict__ in,
                                                unsigned short* __restrict__ out) {
    size_t i = ((size_t)blockIdx.x * 256 + threadIdx.x) * 8;
    f32x4 v0 = *(const f32x4*)(in + i);
    f32x4 v1 = *(const f32x4*)(in + i + 4);
    u16x8 o;
    o[0] = f2bf(v0[0]); o[1] = f2bf(v0[1]); o[2] = f2bf(v0[2]); o[3] = f2bf(v0[3]);
    o[4] = f2bf(v1[0]); o[5] = f2bf(v1[1]); o[6] = f2bf(v1[2]); o[7] = f2bf(v1[3]);
    *(u16x8*)(out + i) = o;
}

// ---- w_real = amp * cos(phase) -> bf16 ----
__global__ __launch_bounds__(256) void wreal_bf16(const float* __restrict__ phase,
                                                  const float* __restrict__ amp,
                                                  unsigned short* __restrict__ out) {
    size_t i = ((size_t)blockIdx.x * 256 + threadIdx.x) * 8;
    f32x4 p0 = *(const f32x4*)(phase + i);
    f32x4 p1 = *(const f32x4*)(phase + i + 4);
    f32x4 a0 = *(const f32x4*)(amp + i);
    f32x4 a1 = *(const f32x4*)(amp + i + 4);
    u16x8 o;
    o[0] = f2bf(a0[0] * cosf(p0[0])); o[1] = f2bf(a0[1] * cosf(p0[1]));
    o[2] = f2bf(a0[2] * cosf(p0[2])); o[3] = f2bf(a0[3] * cosf(p0[3]));
    o[4] = f2bf(a1[0] * cosf(p1[0])); o[5] = f2bf(a1[1] * cosf(p1[1]));
    o[6] = f2bf(a1[2] * cosf(p1[2])); o[7] = f2bf(a1[3] * cosf(p1[3]));
    *(u16x8*)(out + i) = o;
}

// ---- gemm1: resonance[M,256] = x_f32[M,2048] @ basis_bf16[256,2048]^T ----
// Tile 32x256 (x read exactly once), BK=64, 4 waves (wave w -> cols w*64,
// 2 n-frags of 32), mfma_f32_32x32x16_bf16, 2-phase dbuf.
// LDS: A fp32 [32][64] (16B-chunk XOR (row&15) swizzle), B bf16 [256][64]
// (16B-chunk XOR (row&7) swizzle). Both staged with pre-swizzled global src.
__global__ __launch_bounds__(256) void gemm1_fused(const float* __restrict__ A,
                                                   const unsigned short* __restrict__ B,
                                                   unsigned short* __restrict__ C) {
    __shared__ float          Asm[2][32 * 64];    // 16 KB
    __shared__ unsigned short Bsm[2][256 * 64];   // 64 KB

    const int tid  = threadIdx.x;
    const int lane = tid & 63;
    const int wv   = tid >> 6;
    const int bm0  = blockIdx.x * 32;

    // --- staging sources (inverse-swizzled per-lane global addresses) ---
    const float* srcA[2];
#pragma unroll
    for (int q = 0; q < 2; ++q) {
        int L = q * 256 + tid;
        int r = L >> 4, p = L & 15;
        int c = p ^ (r & 15);
        srcA[q] = A + (size_t)(bm0 + r) * K_IN + c * 4;
    }
    const unsigned short* srcB[8];
#pragma unroll
    for (int q = 0; q < 8; ++q) {
        int L = q * 256 + tid;
        int r = L >> 3, p = L & 7;
        int c = p ^ (r & 7);
        srcB[q] = B + (size_t)r * K_IN + c * 8;
    }
    // linear LDS dest offsets (wave-uniform base + lane*16B)
    const int dA = wv * 256 + lane * 4;   // floats, + q*1024
    const int dB = wv * 512 + lane * 8;   // shorts, + q*2048

    f32x16 acc[2];
#pragma unroll
    for (int nf = 0; nf < 2; ++nf)
#pragma unroll
        for (int e = 0; e < 16; ++e) acc[nf][e] = 0.f;

    const int r   = lane & 31;
    const int g   = lane >> 5;
    const int r15 = r & 15;
    const int colb = wv * 64;

    // prologue
#pragma unroll
    for (int q = 0; q < 2; ++q) GLDS(srcA[q], &Asm[0][q * 1024 + dA]);
#pragma unroll
    for (int q = 0; q < 8; ++q) GLDS(srcB[q], &Bsm[0][q * 2048 + dB]);
    __syncthreads();

    for (int t = 0; t < 32; ++t) {
        const int buf = t & 1;
        if (t + 1 < 32) {
            const int k0 = (t + 1) * 64;
#pragma unroll
            for (int q = 0; q < 2; ++q) GLDS(srcA[q] + k0, &Asm[buf ^ 1][q * 1024 + dA]);
#pragma unroll
            for (int q = 0; q < 8; ++q) GLDS(srcB[q] + k0, &Bsm[buf ^ 1][q * 2048 + dB]);
        }

        bf16x8 af[4];
#pragma unroll
        for (int ks = 0; ks < 4; ++ks) {
            const int c0 = g * 2 + ks * 4;
            f32x4 lo = *(const f32x4*)&Asm[buf][r * 64 + ((c0)     ^ r15) * 4];
            f32x4 hi = *(const f32x4*)&Asm[buf][r * 64 + ((c0 + 1) ^ r15) * 4];
            af[ks] = cvt8(lo, hi);
        }
#pragma unroll
        for (int nf = 0; nf < 2; ++nf) {
            const int rB = colb + nf * 32 + r;
            const int r7 = rB & 7;
#pragma unroll
            for (int ks = 0; ks < 4; ++ks) {
                const int cB = g + ks * 2;
                bf16x8 bfrag = *(const bf16x8*)&Bsm[buf][rB * 64 + (cB ^ r7) * 8];
                acc[nf] = __builtin_amdgcn_mfma_f32_32x32x16_bf16(af[ks], bfrag, acc[nf], 0, 0, 0);
            }
        }
        __syncthreads();
    }

    // C/D (32x32): col = lane&31, row = (reg&3) + 8*(reg>>2) + 4*(lane>>5)
#pragma unroll
    for (int nf = 0; nf < 2; ++nf)
#pragma unroll
        for (int reg = 0; reg < 16; ++reg) {
            int row = bm0 + (reg & 3) + 8 * (reg >> 2) + 4 * g;
            int col = colb + nf * 32 + r;
            C[(size_t)row * N_HARM + col] = f2bf(acc[nf][reg]);
        }
}

// ---- gemm2: C[M][NCOLS] = A[M][K] @ B[NCOLS][K]^T  (bf16 in, fp32 out) ----
// Round-1-verified 128x128 / BK=32 / 4-wave structure + 2-phase dbuf prefetch.
template<int K, int NCOLS>
__global__ __launch_bounds__(256) void gemm_bt(const unsigned short* __restrict__ A,
                                               const unsigned short* __restrict__ B,
                                               float* __restrict__ Cv) {
    __shared__ unsigned short As[2][128 * 32];   // 8 KB x2
    __shared__ unsigned short Bs[2][128 * 32];   // 8 KB x2

    const int tid  = threadIdx.x;
    const int lane = tid & 63;
    const int wv   = tid >> 6;
    const int wr   = wv >> 1;
    const int wc   = wv & 1;
    const int bm0  = blockIdx.y * 128;
    const int bn0  = blockIdx.x * 128;

    const int srow = tid >> 2;
    const int scol = (tid & 3) * 8;
    const unsigned short* gA0 = A + (size_t)(bm0 + srow) * K + scol;
    const unsigned short* gA1 = gA0 + (size_t)64 * K;
    const unsigned short* gB0 = B + (size_t)(bn0 + srow) * K + scol;
    const unsigned short* gB1 = gB0 + (size_t)64 * K;
    const int dL0 = wv * 512 + (lane & 63) * 8;          // shorts (issue 0)
    const int dL1 = 2048 + wv * 512 + (lane & 63) * 8;   // shorts (issue 1)

    f32x4 acc[4][4];
#pragma unroll
    for (int i = 0; i < 4; ++i)
#pragma unroll
        for (int j = 0; j < 4; ++j) acc[i][j] = (f32x4){0.f, 0.f, 0.f, 0.f};

    const int frow = lane & 15;
    const int kseg = (lane >> 4) * 8;
    constexpr int NT = K / 32;

    // prologue
    GLDS(gA0, &As[0][dL0]); GLDS(gA1, &As[0][dL1]);
    GLDS(gB0, &Bs[0][dL0]); GLDS(gB1, &Bs[0][dL1]);
    __syncthreads();

    for (int t = 0; t < NT; ++t) {
        const int buf = t & 1;
        if (t + 1 < NT) {
            const int k0 = (t + 1) * 32;
            GLDS(gA0 + k0, &As[buf ^ 1][dL0]); GLDS(gA1 + k0, &As[buf ^ 1][dL1]);
            GLDS(gB0 + k0, &Bs[buf ^ 1][dL0]); GLDS(gB1 + k0, &Bs[buf ^ 1][dL1]);
        }

        bf16x8 af[4], bfr[4];
#pragma unroll
        for (int i = 0; i < 4; ++i) {
            af[i]  = *(const bf16x8*)(&As[buf][(wr * 64 + i * 16 + frow) * 32 + kseg]);
            bfr[i] = *(const bf16x8*)(&Bs[buf][(wc * 64 + i * 16 + frow) * 32 + kseg]);
        }
#pragma unroll
        for (int i = 0; i < 4; ++i)
#pragma unroll
            for (int j = 0; j < 4; ++j)
                acc[i][j] = __builtin_amdgcn_mfma_f32_16x16x32_bf16(af[i], bfr[j], acc[i][j], 0, 0, 0);

        __syncthreads();
    }

#pragma unroll
    for (int i = 0; i < 4; ++i)
#pragma unroll
        for (int j = 0; j < 4; ++j)
#pragma unroll
            for (int rg = 0; rg < 4; ++rg) {
                int row = bm0 + wr * 64 + i * 16 + (lane >> 4) * 4 + rg;
                int col = bn0 + wc * 64 + j * 16 + (lane & 15);
                Cv[(size_t)row * NCOLS + col] = acc[i][j][rg];
            }
}

extern "C" void kernel_launch(void* const* d_in, const int* in_sizes, int n_in,
                              void* d_out, int out_size, void* d_ws, size_t ws_size,
                              hipStream_t stream) {
    const float* x     = (const float*)d_in[0];   // [4,4096,2048]
    const float* basis = (const float*)d_in[1];   // [256,2048]
    const float* phase = (const float*)d_in[2];   // [8192,256]
    const float* amp   = (const float*)d_in[3];   // [8192,256]
    float* out = (float*)d_out;                   // [4,4096,8192] fp32

    char* ws = (char*)d_ws;
    unsigned short* bb  = (unsigned short*)(ws);             // basis bf16: 1048576 B
    unsigned short* wrb = (unsigned short*)(ws + 1048576);   // wreal bf16: 4194304 B
    unsigned short* rb  = (unsigned short*)(ws + 5242880);   // resonance:  8388608 B

    cvt_bf16<<<dim3(256), dim3(256), 0, stream>>>(basis, bb);
    wreal_bf16<<<dim3(1024), dim3(256), 0, stream>>>(phase, amp, wrb);

    // resonance[16384,256] = x @ bb^T  (fp32 A staged to LDS, fused cvt)
    gemm1_fused<<<dim3(M_ROWS / 32), dim3(256), 0, stream>>>(x, bb, rb);
    // out[16384,8192] = rb @ wrb^T     (K=256, N=8192)
    gemm_bt<256, 8192><<<dim3(N_OUT / 128, M_ROWS / 128), dim3(256), 0, stream>>>(rb, wrb, out);
}